// Round 2
// baseline (416.384 us; speedup 1.0000x reference)
//
#include <hip/hip_runtime.h>

#define NB 256   // batch
#define NT 512   // time steps
#define ND 128   // input dim
#define NU 128   // hidden dim
#define NC 64    // classes
#define NM (NB * NT)   // 131072 flat rows
#define YP 136         // LDS row pitch in halfs (272B, 16B-aligned)
#define SCL 2.8853900817779268f  // 2*log2(e): folds tanh 2x arg-scale + e^x -> 2^x

typedef _Float16 half2v __attribute__((ext_vector_type(2)));
typedef _Float16 half4v __attribute__((ext_vector_type(4)));
typedef _Float16 half8v __attribute__((ext_vector_type(8)));
typedef float f32x4 __attribute__((ext_vector_type(4)));
typedef float v2f __attribute__((ext_vector_type(2)));

#define MFMA(a, b, c) __builtin_amdgcn_mfma_f32_16x16x32_f16((a), (b), (c), 0, 0, 0)

// packed f32x2 -> f16x2
__device__ __forceinline__ half2v pk2(float a, float b) {
  return __builtin_bit_cast(half2v, __builtin_amdgcn_cvt_pkrtz(a, b));
}

// tanh from pre-scaled s = 2x*log2e: tanh(x) = 1 - 2/(2^s + 1); exact limits.
__device__ __forceinline__ float tanh_s(float s) {
  float e = __builtin_amdgcn_exp2f(s);
  return fmaf(-2.0f, __builtin_amdgcn_rcpf(e + 1.0f), 1.0f);
}
// y' = th + tanh(s) - 1 = th - 2/(2^s+1): the "-1" shift lets the constant
// 1-vector be folded into the next GEMM's bias via column sums (no +1 op).
__device__ __forceinline__ float ym1(float s, float th) {
  float e = __builtin_amdgcn_exp2f(s);
  return fmaf(-2.0f, __builtin_amdgcn_rcpf(e + 1.0f), th);
}

// LDS-only barrier (no vmem drain -> prefetches/stores stay in flight).
__device__ __forceinline__ void wg_barrier() {
  asm volatile("s_waitcnt lgkmcnt(0)\n\ts_barrier" ::: "memory");
}

// ===================== K1: TH = tanh(x @ W1 + b1) -> f16 =====================
__global__ __launch_bounds__(256, 1) void k1_inproj(
    const float* __restrict__ x, const float* __restrict__ W1,
    const float* __restrict__ b1v, _Float16* __restrict__ TH)
{
  __shared__ _Float16 W1T[ND * YP];  // W1^T[n][k], pre-scaled by SCL
  const int tid = (int)threadIdx.x;
  for (int i = tid; i < ND * NU / 2; i += 256) {
    int n = i & 127, kh = i >> 7;
    half2v p = {(_Float16)(SCL * W1[(size_t)(2 * kh) * NU + n]),
                (_Float16)(SCL * W1[(size_t)(2 * kh + 1) * NU + n])};
    *(half2v*)&W1T[n * YP + 2 * kh] = p;
  }
  __syncthreads();

  const int L = tid & 63, wv = tid >> 6;
  const int v = L & 15, q = L >> 4;
  const int m0 = (int)blockIdx.x * 64 + wv * 16;

  const float* xr = x + (size_t)(m0 + v) * ND + 8 * q;
  half8v xf[4];
#pragma unroll
  for (int kk = 0; kk < 4; ++kk) {
    float4 a = *(const float4*)(xr + 32 * kk);
    float4 b = *(const float4*)(xr + 32 * kk + 4);
    half2v p0 = pk2(a.x, a.y), p1 = pk2(a.z, a.w);
    half2v p2 = pk2(b.x, b.y), p3 = pk2(b.z, b.w);
    xf[kk] = (half8v){p0[0], p0[1], p1[0], p1[1], p2[0], p2[1], p3[0], p3[1]};
  }

#pragma unroll
  for (int ht = 0; ht < 8; ++ht) {
    f32x4 acc;
    {
      float4 bb = *(const float4*)&b1v[16 * ht + 4 * q];
      acc = (f32x4){SCL * bb.x, SCL * bb.y, SCL * bb.z, SCL * bb.w};
    }
#pragma unroll
    for (int kk = 0; kk < 4; ++kk) {
      half8v wa = *(const half8v*)&W1T[(16 * ht + v) * YP + 32 * kk + 8 * q];
      acc = MFMA(wa, xf[kk], acc);
    }
    half2v zlo = pk2(tanh_s(acc[0]), tanh_s(acc[1]));
    half2v zhi = pk2(tanh_s(acc[2]), tanh_s(acc[3]));
    half4v z = {zlo[0], zlo[1], zhi[0], zhi[1]};
    *(half4v*)&TH[(size_t)(m0 + v) * NU + 16 * ht + 4 * q] = z;
  }
}

// ===================== K2: recurrence (2 waves) + head (1 wave) =====================
// 16 blocks x 192 thr. Waves 0,1: hidden slice [64w,64w+64), 16 MFMA/step each.
// Wave 2: classifier head, reads the y'-image post-barrier, 16 MFMA/step, f32 out.
// LDS exchange carries y' = y - 1 (the 1-vector is folded into biases via
// column sums of W2/Wc). 12 KB LDS reads/step vs 32 KB in the 8-wave layout.
__global__ __launch_bounds__(192, 1) void k2_recur(
    const _Float16* __restrict__ TH, const float* __restrict__ W2,
    const float* __restrict__ b2v, const float* __restrict__ Wc,
    const float* __restrict__ bcv, float* __restrict__ out)
{
  __shared__ _Float16 Ybuf[2][16 * YP];  // y' image [v][h], double-buffered

  const int tid = (int)threadIdx.x;
  const int w = tid >> 6;  // 0,1 = recurrence; 2 = head
  const int L = tid & 63;
  const int v = L & 15, q = L >> 4;
  const int b0 = (int)blockIdx.x * 16;
  const _Float16* rd = &Ybuf[0][0] + v * YP + 8 * q;
  const f32x4 zero4 = (f32x4){0.f, 0.f, 0.f, 0.f};

  if (w < 2) {
    // ---------------- recurrence wave ----------------
    half8v w2f[4][4];  // A-frags of W2^T for 4 hidden subtiles, scaled SCL
#pragma unroll
    for (int ht = 0; ht < 4; ++ht)
#pragma unroll
      for (int kk = 0; kk < 4; ++kk) {
        half8v h;
#pragma unroll
        for (int j = 0; j < 8; ++j)
          h[j] = (_Float16)(SCL *
                 W2[(size_t)(32 * kk + 8 * q + j) * NU + 64 * w + 16 * ht + v]);
        w2f[ht][kk] = h;
      }
    f32x4 racc[4], b2f[4];
#pragma unroll
    for (int ht = 0; ht < 4; ++ht) {
      const int h0 = 64 * w + 16 * ht + 4 * q;
      float4 bb = *(const float4*)&b2v[h0];
      racc[ht] = (f32x4){SCL * bb.x, SCL * bb.y, SCL * bb.z, SCL * bb.w};
      // column sums of W2 for the y-1 shift fold: b2' = SCL*(b2 + sum_k W2[k,:])
      f32x4 cs = zero4;
#pragma unroll 4
      for (int k = 0; k < NU; ++k) {
        float4 ww = *(const float4*)&W2[(size_t)k * NU + h0];
        cs += (f32x4){ww.x, ww.y, ww.z, ww.w};
      }
      b2f[ht] = racc[ht] +
                (f32x4){SCL * cs[0], SCL * cs[1], SCL * cs[2], SCL * cs[3]};
      // racc stays SCL*b2: r_0 = SCL*(0@W2 + b2)
    }

    const _Float16* thp = TH + ((size_t)(b0 + v) * NT) * NU + 64 * w + 4 * q;
    _Float16* wr = &Ybuf[0][0] + v * YP + 64 * w + 4 * q;

#define LOADTH(R_, T_)                                                        \
  {                                                                           \
    const _Float16* p_ = thp + (size_t)(T_) * NU;                             \
    R_[0] = *(const half4v*)(p_);                                             \
    R_[1] = *(const half4v*)(p_ + 16);                                        \
    R_[2] = *(const half4v*)(p_ + 32);                                        \
    R_[3] = *(const half4v*)(p_ + 48);                                        \
  }

    half4v rg0[4], rg1[4], rg2[4], rg3[4];  // th ring, depth 4
    LOADTH(rg0, 0) LOADTH(rg1, 1) LOADTH(rg2, 2) LOADTH(rg3, 3)

#define RSTEP(T_, R_, BUF_)                                                   \
  {                                                                           \
    _Pragma("unroll")                                                         \
    for (int ht = 0; ht < 4; ++ht) {                                          \
      half4v t4 = R_[ht];                                                     \
      half2v ylo = pk2(ym1(racc[ht][0], (float)t4[0]),                        \
                       ym1(racc[ht][1], (float)t4[1]));                       \
      half2v yhi = pk2(ym1(racc[ht][2], (float)t4[2]),                        \
                       ym1(racc[ht][3], (float)t4[3]));                       \
      half4v y4 = {ylo[0], ylo[1], yhi[0], yhi[1]};                           \
      *(half4v*)(wr + (BUF_) * (16 * YP) + 16 * ht) = y4;                     \
    }                                                                         \
    {                                                                         \
      int tn = (T_) + 4; tn = tn < NT ? tn : NT - 1;                          \
      LOADTH(R_, tn)                                                          \
    }                                                                         \
    wg_barrier();                                                             \
    {                                                                         \
      half8v yf0 = *(const half8v*)(rd + (BUF_) * (16 * YP) + 0);             \
      half8v yf1 = *(const half8v*)(rd + (BUF_) * (16 * YP) + 32);            \
      half8v yf2 = *(const half8v*)(rd + (BUF_) * (16 * YP) + 64);            \
      half8v yf3 = *(const half8v*)(rd + (BUF_) * (16 * YP) + 96);            \
      _Pragma("unroll")                                                       \
      for (int ht = 0; ht < 4; ++ht) {                                        \
        f32x4 ra = MFMA(w2f[ht][0], yf0, b2f[ht]);                            \
        f32x4 rb = MFMA(w2f[ht][1], yf1, zero4);                              \
        ra = MFMA(w2f[ht][2], yf2, ra);                                       \
        rb = MFMA(w2f[ht][3], yf3, rb);                                       \
        racc[ht] = ra + rb;                                                   \
      }                                                                       \
    }                                                                         \
  }

#pragma unroll 1
    for (int t = 0; t < NT; t += 4) {
      RSTEP(t + 0, rg0, 0)
      RSTEP(t + 1, rg1, 1)
      RSTEP(t + 2, rg2, 0)
      RSTEP(t + 3, rg3, 1)
    }
#undef RSTEP
#undef LOADTH
  } else {
    // ---------------- head wave ----------------
    half8v wcf[4][4];  // A-frags of Wc^T for 4 class subtiles (unscaled)
#pragma unroll
    for (int ct = 0; ct < 4; ++ct)
#pragma unroll
      for (int kk = 0; kk < 4; ++kk) {
        half8v h;
#pragma unroll
        for (int j = 0; j < 8; ++j)
          h[j] = (_Float16)Wc[(size_t)(32 * kk + 8 * q + j) * NC + 16 * ct + v];
        wcf[ct][kk] = h;
      }
    f32x4 bcf[4];
#pragma unroll
    for (int ct = 0; ct < 4; ++ct) {
      const int c0 = 16 * ct + 4 * q;
      float4 bb = *(const float4*)&bcv[c0];
      f32x4 cs = zero4;  // bc' = bc + sum_k Wc[k,:] (y-1 shift fold)
#pragma unroll 4
      for (int k = 0; k < NU; ++k) {
        float4 ww = *(const float4*)&Wc[(size_t)k * NC + c0];
        cs += (f32x4){ww.x, ww.y, ww.z, ww.w};
      }
      bcf[ct] = cs + (f32x4){bb.x, bb.y, bb.z, bb.w};
    }
    float* op = out + ((size_t)(b0 + v) * NT) * NC + 4 * q;

#define HSTEP(T_, BUF_)                                                       \
  {                                                                           \
    wg_barrier();                                                             \
    half8v yf0 = *(const half8v*)(rd + (BUF_) * (16 * YP) + 0);               \
    half8v yf1 = *(const half8v*)(rd + (BUF_) * (16 * YP) + 32);              \
    half8v yf2 = *(const half8v*)(rd + (BUF_) * (16 * YP) + 64);              \
    half8v yf3 = *(const half8v*)(rd + (BUF_) * (16 * YP) + 96);              \
    _Pragma("unroll")                                                         \
    for (int ct = 0; ct < 4; ++ct) {                                          \
      f32x4 oa = MFMA(wcf[ct][0], yf0, bcf[ct]);                              \
      f32x4 ob = MFMA(wcf[ct][1], yf1, zero4);                                \
      oa = MFMA(wcf[ct][2], yf2, oa);                                         \
      ob = MFMA(wcf[ct][3], yf3, ob);                                         \
      f32x4 oo = oa + ob;                                                     \
      *(float4*)(op + (size_t)(T_) * NC + 16 * ct) =                          \
          (float4){oo[0], oo[1], oo[2], oo[3]};                               \
    }                                                                         \
  }

#pragma unroll 1
    for (int t = 0; t < NT; t += 2) {
      HSTEP(t + 0, 0)
      HSTEP(t + 1, 1)
    }
#undef HSTEP
  }
}

// ===================== fallback (round-2 kernel, no workspace) =====================
__device__ __forceinline__ float fast_tanh(float x) {
  float e = __expf(2.0f * x);
  return 1.0f - 2.0f / (e + 1.0f);
}
__device__ __forceinline__ float bcast(float val, int i) {
  return __builtin_bit_cast(float, __builtin_amdgcn_readlane(__builtin_bit_cast(int, val), i));
}

__global__ __launch_bounds__(256, 1) void rnn_fallback(
    const float* __restrict__ x, const float* __restrict__ W1,
    const float* __restrict__ b1v, const float* __restrict__ W2,
    const float* __restrict__ b2v, const float* __restrict__ Wc,
    const float* __restrict__ bcv, float* __restrict__ out)
{
  __shared__ float xring[16][ND];
  __shared__ float pH[2][4][NU];
  __shared__ float pR[2][4][NU];
  __shared__ float pC[2][4][NC];

  const int tid  = (int)threadIdx.x;
  const int lane = tid & 63;
  const int kg   = tid >> 6;
  const int b    = (int)blockIdx.x;
  const float4* xr4 = (const float4*)(x + (size_t)b * NT * ND);

  v2f w1f[32], w2f[32];
  float wcf[32];
#pragma unroll
  for (int i = 0; i < 32; ++i) {
    int k = kg * 32 + i;
    w1f[i] = (v2f){W1[k * NU + lane], W1[k * NU + lane + 64]};
    w2f[i] = (v2f){W2[k * NU + lane], W2[k * NU + lane + 64]};
    wcf[i] = Wc[k * NC + lane];
  }
  const float biasc = bcv[lane];
  float bias1 = 0.f, bias2 = 0.f;
  if (lane < 32) { bias1 = b1v[kg * 32 + lane]; bias2 = b2v[kg * 32 + lane]; }

  float4 stg = make_float4(0.f, 0.f, 0.f, 0.f);
  if (lane < 32) {
    float4 a0 = xr4[(kg + 0) * 32 + lane];
    float4 a1 = xr4[(kg + 4) * 32 + lane];
    ((float4*)xring[kg + 0])[lane] = a0;
    ((float4*)xring[kg + 4])[lane] = a1;
    stg = xr4[(kg + 8) * 32 + lane];
  }
  float yseg = 0.f;
  wg_barrier();

  for (int t = 0; t < NT; ++t) {
    const int pb = t & 1;
    v2f accH0 = {0.f, 0.f}, accH1 = {0.f, 0.f};
    const float4* xb = (const float4*)&xring[t & 15][kg * 32];
#pragma unroll
    for (int i = 0; i < 4; ++i) {
      float4 xa = xb[2 * i];
      float4 xc = xb[2 * i + 1];
      accH0 = w1f[8*i+0] * (v2f){xa.x, xa.x} + accH0;
      accH1 = w1f[8*i+1] * (v2f){xa.y, xa.y} + accH1;
      accH0 = w1f[8*i+2] * (v2f){xa.z, xa.z} + accH0;
      accH1 = w1f[8*i+3] * (v2f){xa.w, xa.w} + accH1;
      accH0 = w1f[8*i+4] * (v2f){xc.x, xc.x} + accH0;
      accH1 = w1f[8*i+5] * (v2f){xc.y, xc.y} + accH1;
      accH0 = w1f[8*i+6] * (v2f){xc.z, xc.z} + accH0;
      accH1 = w1f[8*i+7] * (v2f){xc.w, xc.w} + accH1;
    }
    v2f accH = accH0 + accH1;
    v2f accR0 = {0.f, 0.f}, accR1 = {0.f, 0.f};
    float accC0 = 0.f, accC1 = 0.f;
#pragma unroll
    for (int i = 0; i < 16; ++i) {
      float s0 = bcast(yseg, 2 * i);
      float s1 = bcast(yseg, 2 * i + 1);
      accR0 = w2f[2*i+0] * (v2f){s0, s0} + accR0;
      accR1 = w2f[2*i+1] * (v2f){s1, s1} + accR1;
      accC0 = fmaf(s0, wcf[2*i+0], accC0);
      accC1 = fmaf(s1, wcf[2*i+1], accC1);
    }
    v2f accR = accR0 + accR1;
    float accC = accC0 + accC1;

    pH[pb][kg][lane]      = accH.x;
    pH[pb][kg][lane + 64] = accH.y;
    pR[pb][kg][lane]      = accR.x;
    pR[pb][kg][lane + 64] = accR.y;
    pC[pb][kg][lane]      = accC;

    if (kg == (t & 3)) {
      if (lane < 32) {
        ((float4*)xring[(t + 8) & 15])[lane] = stg;
        int r = t + 12; r = (r < NT) ? r : (NT - 1);
        stg = xr4[r * 32 + lane];
      }
    }
    wg_barrier();
    if (lane < 32) {
      const int j = kg * 32 + lane;
      float hs = bias1, rs = bias2;
#pragma unroll
      for (int g = 0; g < 4; ++g) { hs += pH[pb][g][j]; rs += pR[pb][g][j]; }
      yseg = fast_tanh(hs) + fast_tanh(rs);
    }
    if (kg == ((t + 2) & 3) && t >= 1) {
      float cs = biasc;
#pragma unroll
      for (int g = 0; g < 4; ++g) cs += pC[pb][g][lane];
      out[((size_t)b * NT + (t - 1)) * NC + lane] = cs;
    }
  }
  float accC0 = 0.f, accC1 = 0.f;
#pragma unroll
  for (int i = 0; i < 16; ++i) {
    float s0 = bcast(yseg, 2 * i);
    float s1 = bcast(yseg, 2 * i + 1);
    accC0 = fmaf(s0, wcf[2*i+0], accC0);
    accC1 = fmaf(s1, wcf[2*i+1], accC1);
  }
  pC[0][kg][lane] = accC0 + accC1;
  wg_barrier();
  if (kg == 0) {
    float cs = biasc;
#pragma unroll
    for (int g = 0; g < 4; ++g) cs += pC[0][g][lane];
    out[((size_t)b * NT + (NT - 1)) * NC + lane] = cs;
  }
}

extern "C" void kernel_launch(void* const* d_in, const int* in_sizes, int n_in,
                              void* d_out, int out_size, void* d_ws, size_t ws_size,
                              hipStream_t stream) {
  (void)in_sizes; (void)n_in; (void)out_size;
  const float* x   = (const float*)d_in[0];
  const float* W1  = (const float*)d_in[1];
  const float* b1v = (const float*)d_in[2];
  const float* W2  = (const float*)d_in[3];
  const float* b2v = (const float*)d_in[4];
  const float* Wc  = (const float*)d_in[5];
  const float* bcv = (const float*)d_in[6];
  float* out = (float*)d_out;

  const size_t need = (size_t)NM * NU * 2;  // TH f16 = 32 MiB
  if (ws_size >= need) {
    _Float16* TH = (_Float16*)d_ws;
    hipLaunchKernelGGL(k1_inproj, dim3(NM / 64), dim3(256), 0, stream, x, W1, b1v, TH);
    hipLaunchKernelGGL(k2_recur, dim3(NB / 16), dim3(192), 0, stream,
                       TH, W2, b2v, Wc, bcv, out);
  } else {
    hipLaunchKernelGGL(rnn_fallback, dim3(NB), dim3(256), 0, stream,
                       x, W1, b1v, W2, b2v, Wc, bcv, out);
  }
}

// Round 3
// 341.058 us; speedup vs baseline: 1.2209x; 1.2209x over previous
//
#include <hip/hip_runtime.h>

#define NB 256   // batch
#define NT 512   // time steps
#define ND 128   // input dim
#define NU 128   // hidden dim
#define NC 64    // classes
#define NM (NB * NT)   // 131072 flat rows
#define YP 136         // LDS row pitch in halfs (272B, 16B-aligned)
#define SCL 2.8853900817779268f  // 2*log2(e): folds tanh 2x arg-scale + e^x -> 2^x

typedef _Float16 half2v __attribute__((ext_vector_type(2)));
typedef _Float16 half4v __attribute__((ext_vector_type(4)));
typedef _Float16 half8v __attribute__((ext_vector_type(8)));
typedef float f32x4 __attribute__((ext_vector_type(4)));
typedef float v2f __attribute__((ext_vector_type(2)));

#define MFMA(a, b, c) __builtin_amdgcn_mfma_f32_16x16x32_f16((a), (b), (c), 0, 0, 0)

// packed f32x2 -> f16x2
__device__ __forceinline__ half2v pk2(float a, float b) {
  return __builtin_bit_cast(half2v, __builtin_amdgcn_cvt_pkrtz(a, b));
}

// tanh from pre-scaled s = 2x*log2e: tanh(x) = 1 - 2/(2^s + 1); exact limits.
__device__ __forceinline__ float tanh_s(float s) {
  float e = __builtin_amdgcn_exp2f(s);
  return fmaf(-2.0f, __builtin_amdgcn_rcpf(e + 1.0f), 1.0f);
}
// y' = th + tanh(s) - 1 = th - 2/(2^s+1): the "-1" shift lets the constant
// 1-vector be folded into the next GEMM's bias via column sums of W2.
__device__ __forceinline__ float ym1(float s, float th) {
  float e = __builtin_amdgcn_exp2f(s);
  return fmaf(-2.0f, __builtin_amdgcn_rcpf(e + 1.0f), th);
}

// LDS-only barrier (no vmem drain -> prefetches/stores stay in flight).
__device__ __forceinline__ void wg_barrier() {
  asm volatile("s_waitcnt lgkmcnt(0)\n\ts_barrier" ::: "memory");
}

// ===================== K1: TH = tanh(x @ W1 + b1) -> f16 =====================
__global__ __launch_bounds__(256, 1) void k1_inproj(
    const float* __restrict__ x, const float* __restrict__ W1,
    const float* __restrict__ b1v, _Float16* __restrict__ TH)
{
  __shared__ _Float16 W1T[ND * YP];  // W1^T[n][k], pre-scaled by SCL
  const int tid = (int)threadIdx.x;
  for (int i = tid; i < ND * NU / 2; i += 256) {
    int n = i & 127, kh = i >> 7;
    half2v p = {(_Float16)(SCL * W1[(size_t)(2 * kh) * NU + n]),
                (_Float16)(SCL * W1[(size_t)(2 * kh + 1) * NU + n])};
    *(half2v*)&W1T[n * YP + 2 * kh] = p;
  }
  __syncthreads();

  const int L = tid & 63, wv = tid >> 6;
  const int v = L & 15, q = L >> 4;
  const int m0 = (int)blockIdx.x * 64 + wv * 16;

  const float* xr = x + (size_t)(m0 + v) * ND + 8 * q;
  half8v xf[4];
#pragma unroll
  for (int kk = 0; kk < 4; ++kk) {
    float4 a = *(const float4*)(xr + 32 * kk);
    float4 b = *(const float4*)(xr + 32 * kk + 4);
    half2v p0 = pk2(a.x, a.y), p1 = pk2(a.z, a.w);
    half2v p2 = pk2(b.x, b.y), p3 = pk2(b.z, b.w);
    xf[kk] = (half8v){p0[0], p0[1], p1[0], p1[1], p2[0], p2[1], p3[0], p3[1]};
  }

#pragma unroll
  for (int ht = 0; ht < 8; ++ht) {
    f32x4 acc;
    {
      float4 bb = *(const float4*)&b1v[16 * ht + 4 * q];
      acc = (f32x4){SCL * bb.x, SCL * bb.y, SCL * bb.z, SCL * bb.w};
    }
#pragma unroll
    for (int kk = 0; kk < 4; ++kk) {
      half8v wa = *(const half8v*)&W1T[(16 * ht + v) * YP + 32 * kk + 8 * q];
      acc = MFMA(wa, xf[kk], acc);
    }
    half2v zlo = pk2(tanh_s(acc[0]), tanh_s(acc[1]));
    half2v zhi = pk2(tanh_s(acc[2]), tanh_s(acc[3]));
    half4v z = {zlo[0], zlo[1], zhi[0], zhi[1]};
    *(half4v*)&TH[(size_t)(m0 + v) * NU + 16 * ht + 4 * q] = z;
  }
}

// ===================== K2: serial recurrence, 4 waves =====================
// 16 blocks x 256 thr (4 waves). Wave w owns hidden slice [32w,32w+32):
// 8 MFMA/step (~130 cyc issue/SIMD), 8 tanh/step (~96 cyc VALU), LDS reads
// 16 KB/step (4 waves x 4 KB) -- the minimum of the per-wave-issue vs
// shared-LDS/barrier cost curve (8 waves: 32 KB reads; 2 waves: 260 cyc MFMA).
// Exchange carries y' = y-1 (1-vector folded into b2 via column sums);
// global Y store gets +1 re-applied via one packed-f16 add (off-chain).
__global__ __launch_bounds__(256, 1) void k2_recur(
    const _Float16* __restrict__ TH, const float* __restrict__ W2,
    const float* __restrict__ b2v, _Float16* __restrict__ Yws)
{
  __shared__ _Float16 Ybuf[2][16 * YP];  // y' image [v][h], double-buffered

  const int tid = (int)threadIdx.x;
  const int w = tid >> 6;  // hidden slice 0..3
  const int L = tid & 63;
  const int v = L & 15, q = L >> 4;
  const int b0 = (int)blockIdx.x * 16;
  const _Float16* rd = &Ybuf[0][0] + v * YP + 8 * q;
  const f32x4 zero4 = (f32x4){0.f, 0.f, 0.f, 0.f};

  // A-frags of W2^T for 2 hidden subtiles, scaled SCL
  half8v w2f[2][4];
#pragma unroll
  for (int ht = 0; ht < 2; ++ht)
#pragma unroll
    for (int kk = 0; kk < 4; ++kk) {
      half8v h;
#pragma unroll
      for (int j = 0; j < 8; ++j)
        h[j] = (_Float16)(SCL *
               W2[(size_t)(32 * kk + 8 * q + j) * NU + 32 * w + 16 * ht + v]);
      w2f[ht][kk] = h;
    }
  f32x4 racc[2], b2f[2];
#pragma unroll
  for (int ht = 0; ht < 2; ++ht) {
    const int h0 = 32 * w + 16 * ht + 4 * q;
    float4 bb = *(const float4*)&b2v[h0];
    racc[ht] = (f32x4){SCL * bb.x, SCL * bb.y, SCL * bb.z, SCL * bb.w};
    // b2' = SCL*(b2 + sum_k W2[k,:])  (y-1 shift fold); racc stays SCL*b2.
    f32x4 cs = zero4;
#pragma unroll 4
    for (int k = 0; k < NU; ++k) {
      float4 ww = *(const float4*)&W2[(size_t)k * NU + h0];
      cs += (f32x4){ww.x, ww.y, ww.z, ww.w};
    }
    b2f[ht] = racc[ht] +
              (f32x4){SCL * cs[0], SCL * cs[1], SCL * cs[2], SCL * cs[3]};
  }

  const _Float16* thp = TH + ((size_t)(b0 + v) * NT) * NU + 32 * w + 4 * q;
  _Float16* yp = Yws + ((size_t)(b0 + v) * NT) * NU + 32 * w + 4 * q;
  _Float16* wr = &Ybuf[0][0] + v * YP + 32 * w + 4 * q;
  const half4v one4 = {(_Float16)1.f, (_Float16)1.f, (_Float16)1.f, (_Float16)1.f};

#define LOADTH(R_, T_)                                                        \
  {                                                                           \
    const _Float16* p_ = thp + (size_t)(T_) * NU;                             \
    R_[0] = *(const half4v*)(p_);                                             \
    R_[1] = *(const half4v*)(p_ + 16);                                        \
  }

  half4v rg0[2], rg1[2], rg2[2], rg3[2];  // th ring, depth 4
  LOADTH(rg0, 0) LOADTH(rg1, 1) LOADTH(rg2, 2) LOADTH(rg3, 3)

#define RSTEP(T_, R_, BUF_)                                                   \
  {                                                                           \
    _Pragma("unroll")                                                         \
    for (int ht = 0; ht < 2; ++ht) {                                          \
      half4v t4 = R_[ht];                                                     \
      half2v ylo = pk2(ym1(racc[ht][0], (float)t4[0]),                        \
                       ym1(racc[ht][1], (float)t4[1]));                       \
      half2v yhi = pk2(ym1(racc[ht][2], (float)t4[2]),                        \
                       ym1(racc[ht][3], (float)t4[3]));                       \
      half4v y4 = {ylo[0], ylo[1], yhi[0], yhi[1]};                           \
      *(half4v*)(wr + (BUF_) * (16 * YP) + 16 * ht) = y4;                     \
      *(half4v*)(yp + (size_t)(T_) * NU + 16 * ht) = y4 + one4;               \
    }                                                                         \
    {                                                                         \
      int tn = (T_) + 4; tn = tn < NT ? tn : NT - 1;                          \
      LOADTH(R_, tn)                                                          \
    }                                                                         \
    wg_barrier();                                                             \
    {                                                                         \
      half8v yf0 = *(const half8v*)(rd + (BUF_) * (16 * YP) + 0);             \
      half8v yf1 = *(const half8v*)(rd + (BUF_) * (16 * YP) + 32);            \
      half8v yf2 = *(const half8v*)(rd + (BUF_) * (16 * YP) + 64);            \
      half8v yf3 = *(const half8v*)(rd + (BUF_) * (16 * YP) + 96);            \
      _Pragma("unroll")                                                       \
      for (int ht = 0; ht < 2; ++ht) {                                        \
        f32x4 ra = MFMA(w2f[ht][0], yf0, b2f[ht]);                            \
        f32x4 rb = MFMA(w2f[ht][1], yf1, zero4);                              \
        ra = MFMA(w2f[ht][2], yf2, ra);                                       \
        rb = MFMA(w2f[ht][3], yf3, rb);                                       \
        racc[ht] = ra + rb;                                                   \
      }                                                                       \
    }                                                                         \
  }

#pragma unroll 1
  for (int t = 0; t < NT; t += 4) {
    RSTEP(t + 0, rg0, 0)
    RSTEP(t + 1, rg1, 1)
    RSTEP(t + 2, rg2, 0)
    RSTEP(t + 3, rg3, 1)
  }
#undef RSTEP
#undef LOADTH
}

// ===================== K3: out = Y @ Wc + bc =====================
__global__ __launch_bounds__(256, 1) void k3_head(
    const _Float16* __restrict__ Y, const float* __restrict__ Wc,
    const float* __restrict__ bcv, float* __restrict__ out)
{
  __shared__ _Float16 WcT[NC * YP];  // Wc^T[c][k]
  const int tid = (int)threadIdx.x;
  for (int i = tid; i < NU * NC; i += 256) {
    int k = i >> 6, c = i & 63;
    WcT[c * YP + k] = (_Float16)Wc[i];
  }
  __syncthreads();

  const int L = tid & 63, wv = tid >> 6;
  const int v = L & 15, q = L >> 4;
  const int m0 = (int)blockIdx.x * 64 + wv * 16;

  const _Float16* yr = Y + (size_t)(m0 + v) * NU + 8 * q;
  half8v yf[4];
#pragma unroll
  for (int kk = 0; kk < 4; ++kk) yf[kk] = *(const half8v*)(yr + 32 * kk);

  float* op = out + (size_t)(m0 + v) * NC + 4 * q;
#pragma unroll
  for (int ct = 0; ct < 4; ++ct) {
    f32x4 acc;
    {
      float4 bb = *(const float4*)&bcv[16 * ct + 4 * q];
      acc = (f32x4){bb.x, bb.y, bb.z, bb.w};
    }
#pragma unroll
    for (int kk = 0; kk < 4; ++kk) {
      half8v wa = *(const half8v*)&WcT[(16 * ct + v) * YP + 32 * kk + 8 * q];
      acc = MFMA(wa, yf[kk], acc);
    }
    *(float4*)(op + 16 * ct) = (float4){acc[0], acc[1], acc[2], acc[3]};
  }
}

// ===================== fallback (round-2 kernel, no workspace) =====================
__device__ __forceinline__ float fast_tanh(float x) {
  float e = __expf(2.0f * x);
  return 1.0f - 2.0f / (e + 1.0f);
}
__device__ __forceinline__ float bcast(float val, int i) {
  return __builtin_bit_cast(float, __builtin_amdgcn_readlane(__builtin_bit_cast(int, val), i));
}

__global__ __launch_bounds__(256, 1) void rnn_fallback(
    const float* __restrict__ x, const float* __restrict__ W1,
    const float* __restrict__ b1v, const float* __restrict__ W2,
    const float* __restrict__ b2v, const float* __restrict__ Wc,
    const float* __restrict__ bcv, float* __restrict__ out)
{
  __shared__ float xring[16][ND];
  __shared__ float pH[2][4][NU];
  __shared__ float pR[2][4][NU];
  __shared__ float pC[2][4][NC];

  const int tid  = (int)threadIdx.x;
  const int lane = tid & 63;
  const int kg   = tid >> 6;
  const int b    = (int)blockIdx.x;
  const float4* xr4 = (const float4*)(x + (size_t)b * NT * ND);

  v2f w1f[32], w2f[32];
  float wcf[32];
#pragma unroll
  for (int i = 0; i < 32; ++i) {
    int k = kg * 32 + i;
    w1f[i] = (v2f){W1[k * NU + lane], W1[k * NU + lane + 64]};
    w2f[i] = (v2f){W2[k * NU + lane], W2[k * NU + lane + 64]};
    wcf[i] = Wc[k * NC + lane];
  }
  const float biasc = bcv[lane];
  float bias1 = 0.f, bias2 = 0.f;
  if (lane < 32) { bias1 = b1v[kg * 32 + lane]; bias2 = b2v[kg * 32 + lane]; }

  float4 stg = make_float4(0.f, 0.f, 0.f, 0.f);
  if (lane < 32) {
    float4 a0 = xr4[(kg + 0) * 32 + lane];
    float4 a1 = xr4[(kg + 4) * 32 + lane];
    ((float4*)xring[kg + 0])[lane] = a0;
    ((float4*)xring[kg + 4])[lane] = a1;
    stg = xr4[(kg + 8) * 32 + lane];
  }
  float yseg = 0.f;
  wg_barrier();

  for (int t = 0; t < NT; ++t) {
    const int pb = t & 1;
    v2f accH0 = {0.f, 0.f}, accH1 = {0.f, 0.f};
    const float4* xb = (const float4*)&xring[t & 15][kg * 32];
#pragma unroll
    for (int i = 0; i < 4; ++i) {
      float4 xa = xb[2 * i];
      float4 xc = xb[2 * i + 1];
      accH0 = w1f[8*i+0] * (v2f){xa.x, xa.x} + accH0;
      accH1 = w1f[8*i+1] * (v2f){xa.y, xa.y} + accH1;
      accH0 = w1f[8*i+2] * (v2f){xa.z, xa.z} + accH0;
      accH1 = w1f[8*i+3] * (v2f){xa.w, xa.w} + accH1;
      accH0 = w1f[8*i+4] * (v2f){xc.x, xc.x} + accH0;
      accH1 = w1f[8*i+5] * (v2f){xc.y, xc.y} + accH1;
      accH0 = w1f[8*i+6] * (v2f){xc.z, xc.z} + accH0;
      accH1 = w1f[8*i+7] * (v2f){xc.w, xc.w} + accH1;
    }
    v2f accH = accH0 + accH1;
    v2f accR0 = {0.f, 0.f}, accR1 = {0.f, 0.f};
    float accC0 = 0.f, accC1 = 0.f;
#pragma unroll
    for (int i = 0; i < 16; ++i) {
      float s0 = bcast(yseg, 2 * i);
      float s1 = bcast(yseg, 2 * i + 1);
      accR0 = w2f[2*i+0] * (v2f){s0, s0} + accR0;
      accR1 = w2f[2*i+1] * (v2f){s1, s1} + accR1;
      accC0 = fmaf(s0, wcf[2*i+0], accC0);
      accC1 = fmaf(s1, wcf[2*i+1], accC1);
    }
    v2f accR = accR0 + accR1;
    float accC = accC0 + accC1;

    pH[pb][kg][lane]      = accH.x;
    pH[pb][kg][lane + 64] = accH.y;
    pR[pb][kg][lane]      = accR.x;
    pR[pb][kg][lane + 64] = accR.y;
    pC[pb][kg][lane]      = accC;

    if (kg == (t & 3)) {
      if (lane < 32) {
        ((float4*)xring[(t + 8) & 15])[lane] = stg;
        int r = t + 12; r = (r < NT) ? r : (NT - 1);
        stg = xr4[r * 32 + lane];
      }
    }
    wg_barrier();
    if (lane < 32) {
      const int j = kg * 32 + lane;
      float hs = bias1, rs = bias2;
#pragma unroll
      for (int g = 0; g < 4; ++g) { hs += pH[pb][g][j]; rs += pR[pb][g][j]; }
      yseg = fast_tanh(hs) + fast_tanh(rs);
    }
    if (kg == ((t + 2) & 3) && t >= 1) {
      float cs = biasc;
#pragma unroll
      for (int g = 0; g < 4; ++g) cs += pC[pb][g][lane];
      out[((size_t)b * NT + (t - 1)) * NC + lane] = cs;
    }
  }
  float accC0 = 0.f, accC1 = 0.f;
#pragma unroll
  for (int i = 0; i < 16; ++i) {
    float s0 = bcast(yseg, 2 * i);
    float s1 = bcast(yseg, 2 * i + 1);
    accC0 = fmaf(s0, wcf[2*i+0], accC0);
    accC1 = fmaf(s1, wcf[2*i+1], accC1);
  }
  pC[0][kg][lane] = accC0 + accC1;
  wg_barrier();
  if (kg == 0) {
    float cs = biasc;
#pragma unroll
    for (int g = 0; g < 4; ++g) cs += pC[0][g][lane];
    out[((size_t)b * NT + (NT - 1)) * NC + lane] = cs;
  }
}

extern "C" void kernel_launch(void* const* d_in, const int* in_sizes, int n_in,
                              void* d_out, int out_size, void* d_ws, size_t ws_size,
                              hipStream_t stream) {
  (void)in_sizes; (void)n_in; (void)out_size;
  const float* x   = (const float*)d_in[0];
  const float* W1  = (const float*)d_in[1];
  const float* b1v = (const float*)d_in[2];
  const float* W2  = (const float*)d_in[3];
  const float* b2v = (const float*)d_in[4];
  const float* Wc  = (const float*)d_in[5];
  const float* bcv = (const float*)d_in[6];
  float* out = (float*)d_out;

  const size_t need = (size_t)NM * NU * 2 * 2;  // TH + Y, f16 each = 64 MiB
  if (ws_size >= need) {
    _Float16* TH = (_Float16*)d_ws;
    _Float16* Yw = TH + (size_t)NM * NU;
    hipLaunchKernelGGL(k1_inproj, dim3(NM / 64), dim3(256), 0, stream, x, W1, b1v, TH);
    hipLaunchKernelGGL(k2_recur, dim3(NB / 16), dim3(256), 0, stream, TH, W2, b2v, Yw);
    hipLaunchKernelGGL(k3_head, dim3(NM / 64), dim3(256), 0, stream, Yw, Wc, bcv, out);
  } else {
    hipLaunchKernelGGL(rnn_fallback, dim3(NB), dim3(256), 0, stream,
                       x, W1, b1v, W2, b2v, Wc, bcv, out);
  }
}

// Round 4
// 303.498 us; speedup vs baseline: 1.3719x; 1.1238x over previous
//
#include <hip/hip_runtime.h>

#define NB 256   // batch
#define NT 512   // time steps
#define ND 128   // input dim
#define NU 128   // hidden dim
#define NC 64    // classes
#define NM (NB * NT)   // 131072 flat rows
#define YP 136         // LDS row pitch in halfs (272B, 16B-aligned)
#define SCL 2.8853900817779268f  // 2*log2(e): folds tanh 2x arg-scale + e^x -> 2^x

typedef _Float16 half2v __attribute__((ext_vector_type(2)));
typedef _Float16 half4v __attribute__((ext_vector_type(4)));
typedef _Float16 half8v __attribute__((ext_vector_type(8)));
typedef float f32x4 __attribute__((ext_vector_type(4)));
typedef float v2f __attribute__((ext_vector_type(2)));

#define MFMA(a, b, c) __builtin_amdgcn_mfma_f32_16x16x32_f16((a), (b), (c), 0, 0, 0)

// packed f32x2 -> f16x2
__device__ __forceinline__ half2v pk2(float a, float b) {
  return __builtin_bit_cast(half2v, __builtin_amdgcn_cvt_pkrtz(a, b));
}

// tanh from pre-scaled s = 2x*log2e: tanh(x) = 1 - 2/(2^s + 1); exact limits.
__device__ __forceinline__ float tanh_s(float s) {
  float e = __builtin_amdgcn_exp2f(s);
  return fmaf(-2.0f, __builtin_amdgcn_rcpf(e + 1.0f), 1.0f);
}
// y' = th + tanh(s) - 1 = th - 2/(2^s+1): the "-1" shift lets the constant
// 1-vector be folded into the next GEMM's bias via column sums of W2/Wc.
__device__ __forceinline__ float ym1(float s, float th) {
  float e = __builtin_amdgcn_exp2f(s);
  return fmaf(-2.0f, __builtin_amdgcn_rcpf(e + 1.0f), th);
}

// LDS-only barrier (no vmem drain -> prefetches/stores stay in flight).
__device__ __forceinline__ void wg_barrier() {
  asm volatile("s_waitcnt lgkmcnt(0)\n\ts_barrier" ::: "memory");
}

// ===================== K1: TH = tanh(x @ W1 + b1) -> f16 =====================
__global__ __launch_bounds__(256, 1) void k1_inproj(
    const float* __restrict__ x, const float* __restrict__ W1,
    const float* __restrict__ b1v, _Float16* __restrict__ TH)
{
  __shared__ _Float16 W1T[ND * YP];  // W1^T[n][k], pre-scaled by SCL
  const int tid = (int)threadIdx.x;
  for (int i = tid; i < ND * NU / 2; i += 256) {
    int n = i & 127, kh = i >> 7;
    half2v p = {(_Float16)(SCL * W1[(size_t)(2 * kh) * NU + n]),
                (_Float16)(SCL * W1[(size_t)(2 * kh + 1) * NU + n])};
    *(half2v*)&W1T[n * YP + 2 * kh] = p;
  }
  __syncthreads();

  const int L = tid & 63, wv = tid >> 6;
  const int v = L & 15, q = L >> 4;
  const int m0 = (int)blockIdx.x * 64 + wv * 16;

  const float* xr = x + (size_t)(m0 + v) * ND + 8 * q;
  half8v xf[4];
#pragma unroll
  for (int kk = 0; kk < 4; ++kk) {
    float4 a = *(const float4*)(xr + 32 * kk);
    float4 b = *(const float4*)(xr + 32 * kk + 4);
    half2v p0 = pk2(a.x, a.y), p1 = pk2(a.z, a.w);
    half2v p2 = pk2(b.x, b.y), p3 = pk2(b.z, b.w);
    xf[kk] = (half8v){p0[0], p0[1], p1[0], p1[1], p2[0], p2[1], p3[0], p3[1]};
  }

#pragma unroll
  for (int ht = 0; ht < 8; ++ht) {
    f32x4 acc;
    {
      float4 bb = *(const float4*)&b1v[16 * ht + 4 * q];
      acc = (f32x4){SCL * bb.x, SCL * bb.y, SCL * bb.z, SCL * bb.w};
    }
#pragma unroll
    for (int kk = 0; kk < 4; ++kk) {
      half8v wa = *(const half8v*)&W1T[(16 * ht + v) * YP + 32 * kk + 8 * q];
      acc = MFMA(wa, xf[kk], acc);
    }
    half2v zlo = pk2(tanh_s(acc[0]), tanh_s(acc[1]));
    half2v zhi = pk2(tanh_s(acc[2]), tanh_s(acc[3]));
    half4v z = {zlo[0], zlo[1], zhi[0], zhi[1]};
    *(half4v*)&TH[(size_t)(m0 + v) * NU + 16 * ht + 4 * q] = z;
  }
}

// ===================== K2: recurrence (8 thin waves) + head (2 waves) =====================
// 16 blocks x 640 thr. Waves 0..7: hidden tile [16w,16w+16), 4 MFMA + 4 tanh
// per step (measured optimum: 8w=825cyc < 4w=947 < 2w=1340 per step).
// Waves 8,9: classifier head, 2 class tiles each (8 MFMA/step), off the
// recurrence chain; join the same barrier ring (512 calls each path) and
// write `out` directly -> no k3, no Y workspace, rec waves store nothing.
// Exchange carries y' = y-1 (1-vector folded into b2/bc via column sums).
// Race-safety: head reads buf[p] of step t between barriers #t+1 and #t+2;
// rec overwrites buf[p] (step t+2) only after barrier #t+2. Barrier counts
// are equal (one per step in both paths).
__global__ __launch_bounds__(640, 1) void k2_recur(
    const _Float16* __restrict__ TH, const float* __restrict__ W2,
    const float* __restrict__ b2v, const float* __restrict__ Wc,
    const float* __restrict__ bcv, float* __restrict__ out)
{
  __shared__ _Float16 Ybuf[2][16 * YP];  // y' image [v][h], double-buffered

  const int tid = (int)threadIdx.x;
  const int w = tid >> 6;  // 0..7 recurrence, 8..9 head
  const int L = tid & 63;
  const int v = L & 15, q = L >> 4;
  const int b0 = (int)blockIdx.x * 16;
  const _Float16* rd = &Ybuf[0][0] + v * YP + 8 * q;
  const f32x4 zero4 = (f32x4){0.f, 0.f, 0.f, 0.f};

  if (w < 8) {
    // ---------------- recurrence wave: hidden tile [16w,16w+16) ----------------
    half8v w2f[4];  // A-frags of W2^T, scaled SCL
#pragma unroll
    for (int kk = 0; kk < 4; ++kk) {
      half8v h;
#pragma unroll
      for (int j = 0; j < 8; ++j)
        h[j] = (_Float16)(SCL * W2[(size_t)(32 * kk + 8 * q + j) * NU + 16 * w + v]);
      w2f[kk] = h;
    }
    f32x4 racc, b2f;
    {
      const int h0 = 16 * w + 4 * q;
      float4 bb = *(const float4*)&b2v[h0];
      racc = (f32x4){SCL * bb.x, SCL * bb.y, SCL * bb.z, SCL * bb.w};
      // b2' = SCL*(b2 + sum_k W2[k,:])  (y-1 shift fold); racc stays SCL*b2.
      f32x4 cs = zero4;
#pragma unroll 4
      for (int k = 0; k < NU; ++k) {
        float4 ww = *(const float4*)&W2[(size_t)k * NU + h0];
        cs += (f32x4){ww.x, ww.y, ww.z, ww.w};
      }
      b2f = racc + (f32x4){SCL * cs[0], SCL * cs[1], SCL * cs[2], SCL * cs[3]};
    }

    const _Float16* thp = TH + ((size_t)(b0 + v) * NT) * NU + 16 * w + 4 * q;
    _Float16* wr = &Ybuf[0][0] + v * YP + 16 * w + 4 * q;

    // th prefetch ring (4 deep), one 8B load per step
    half4v thr0 = *(const half4v*)(thp + 0 * NU);
    half4v thr1 = *(const half4v*)(thp + 1 * NU);
    half4v thr2 = *(const half4v*)(thp + 2 * NU);
    half4v thr3 = *(const half4v*)(thp + 3 * NU);

#define RSTEP(T_, THR_, BUF_)                                                 \
  {                                                                           \
    half2v ylo = pk2(ym1(racc[0], (float)THR_[0]),                            \
                     ym1(racc[1], (float)THR_[1]));                           \
    half2v yhi = pk2(ym1(racc[2], (float)THR_[2]),                            \
                     ym1(racc[3], (float)THR_[3]));                           \
    half4v y4 = {ylo[0], ylo[1], yhi[0], yhi[1]};                             \
    *(half4v*)(wr + (BUF_) * (16 * YP)) = y4;                                 \
    {                                                                         \
      int tn = (T_) + 4; tn = tn < NT ? tn : NT - 1;                          \
      THR_ = *(const half4v*)(thp + (size_t)tn * NU);                         \
    }                                                                         \
    wg_barrier();                                                             \
    {                                                                         \
      half8v yf0 = *(const half8v*)(rd + (BUF_) * (16 * YP) + 0);             \
      half8v yf1 = *(const half8v*)(rd + (BUF_) * (16 * YP) + 32);            \
      half8v yf2 = *(const half8v*)(rd + (BUF_) * (16 * YP) + 64);            \
      half8v yf3 = *(const half8v*)(rd + (BUF_) * (16 * YP) + 96);            \
      f32x4 ra = MFMA(w2f[0], yf0, b2f);  /* two independent 2-chains */      \
      f32x4 rb = MFMA(w2f[1], yf1, zero4);                                    \
      ra = MFMA(w2f[2], yf2, ra);                                             \
      rb = MFMA(w2f[3], yf3, rb);                                             \
      racc = ra + rb;                                                         \
    }                                                                         \
  }

#pragma unroll 1
    for (int t = 0; t < NT; t += 4) {
      RSTEP(t + 0, thr0, 0)
      RSTEP(t + 1, thr1, 1)
      RSTEP(t + 2, thr2, 0)
      RSTEP(t + 3, thr3, 1)
    }
#undef RSTEP
  } else {
    // ---------------- head wave hw = w-8: class tiles {2hw, 2hw+1} ----------------
    const int hw = w - 8;
    half8v wcf[2][4];
    f32x4 bcf[2];
#pragma unroll
    for (int c2 = 0; c2 < 2; ++c2) {
      const int ct = 2 * hw + c2;
#pragma unroll
      for (int kk = 0; kk < 4; ++kk) {
        half8v h;
#pragma unroll
        for (int j = 0; j < 8; ++j)
          h[j] = (_Float16)Wc[(size_t)(32 * kk + 8 * q + j) * NC + 16 * ct + v];
        wcf[c2][kk] = h;
      }
      const int c0 = 16 * ct + 4 * q;
      float4 bb = *(const float4*)&bcv[c0];
      f32x4 cs = zero4;  // bc' = bc + sum_k Wc[k,:] (y-1 shift fold)
#pragma unroll 4
      for (int k = 0; k < NU; ++k) {
        float4 ww = *(const float4*)&Wc[(size_t)k * NC + c0];
        cs += (f32x4){ww.x, ww.y, ww.z, ww.w};
      }
      bcf[c2] = cs + (f32x4){bb.x, bb.y, bb.z, bb.w};
    }
    float* op = out + ((size_t)(b0 + v) * NT) * NC + 4 * q;

#define HSTEP(T_, BUF_)                                                       \
  {                                                                           \
    wg_barrier();                                                             \
    half8v yf0 = *(const half8v*)(rd + (BUF_) * (16 * YP) + 0);               \
    half8v yf1 = *(const half8v*)(rd + (BUF_) * (16 * YP) + 32);              \
    half8v yf2 = *(const half8v*)(rd + (BUF_) * (16 * YP) + 64);              \
    half8v yf3 = *(const half8v*)(rd + (BUF_) * (16 * YP) + 96);              \
    _Pragma("unroll")                                                         \
    for (int c2 = 0; c2 < 2; ++c2) {                                          \
      f32x4 oa = MFMA(wcf[c2][0], yf0, bcf[c2]);                              \
      f32x4 ob = MFMA(wcf[c2][1], yf1, zero4);                                \
      oa = MFMA(wcf[c2][2], yf2, oa);                                         \
      ob = MFMA(wcf[c2][3], yf3, ob);                                         \
      f32x4 oo = oa + ob;                                                     \
      *(float4*)(op + (size_t)(T_) * NC + 16 * (2 * hw + c2)) =               \
          (float4){oo[0], oo[1], oo[2], oo[3]};                               \
    }                                                                         \
  }

#pragma unroll 1
    for (int t = 0; t < NT; t += 2) {
      HSTEP(t + 0, 0)
      HSTEP(t + 1, 1)
    }
#undef HSTEP
  }
}

// ===================== fallback (round-2 kernel, no workspace) =====================
__device__ __forceinline__ float fast_tanh(float x) {
  float e = __expf(2.0f * x);
  return 1.0f - 2.0f / (e + 1.0f);
}
__device__ __forceinline__ float bcast(float val, int i) {
  return __builtin_bit_cast(float, __builtin_amdgcn_readlane(__builtin_bit_cast(int, val), i));
}

__global__ __launch_bounds__(256, 1) void rnn_fallback(
    const float* __restrict__ x, const float* __restrict__ W1,
    const float* __restrict__ b1v, const float* __restrict__ W2,
    const float* __restrict__ b2v, const float* __restrict__ Wc,
    const float* __restrict__ bcv, float* __restrict__ out)
{
  __shared__ float xring[16][ND];
  __shared__ float pH[2][4][NU];
  __shared__ float pR[2][4][NU];
  __shared__ float pC[2][4][NC];

  const int tid  = (int)threadIdx.x;
  const int lane = tid & 63;
  const int kg   = tid >> 6;
  const int b    = (int)blockIdx.x;
  const float4* xr4 = (const float4*)(x + (size_t)b * NT * ND);

  v2f w1f[32], w2f[32];
  float wcf[32];
#pragma unroll
  for (int i = 0; i < 32; ++i) {
    int k = kg * 32 + i;
    w1f[i] = (v2f){W1[k * NU + lane], W1[k * NU + lane + 64]};
    w2f[i] = (v2f){W2[k * NU + lane], W2[k * NU + lane + 64]};
    wcf[i] = Wc[k * NC + lane];
  }
  const float biasc = bcv[lane];
  float bias1 = 0.f, bias2 = 0.f;
  if (lane < 32) { bias1 = b1v[kg * 32 + lane]; bias2 = b2v[kg * 32 + lane]; }

  float4 stg = make_float4(0.f, 0.f, 0.f, 0.f);
  if (lane < 32) {
    float4 a0 = xr4[(kg + 0) * 32 + lane];
    float4 a1 = xr4[(kg + 4) * 32 + lane];
    ((float4*)xring[kg + 0])[lane] = a0;
    ((float4*)xring[kg + 4])[lane] = a1;
    stg = xr4[(kg + 8) * 32 + lane];
  }
  float yseg = 0.f;
  wg_barrier();

  for (int t = 0; t < NT; ++t) {
    const int pb = t & 1;
    v2f accH0 = {0.f, 0.f}, accH1 = {0.f, 0.f};
    const float4* xb = (const float4*)&xring[t & 15][kg * 32];
#pragma unroll
    for (int i = 0; i < 4; ++i) {
      float4 xa = xb[2 * i];
      float4 xc = xb[2 * i + 1];
      accH0 = w1f[8*i+0] * (v2f){xa.x, xa.x} + accH0;
      accH1 = w1f[8*i+1] * (v2f){xa.y, xa.y} + accH1;
      accH0 = w1f[8*i+2] * (v2f){xa.z, xa.z} + accH0;
      accH1 = w1f[8*i+3] * (v2f){xa.w, xa.w} + accH1;
      accH0 = w1f[8*i+4] * (v2f){xc.x, xc.x} + accH0;
      accH1 = w1f[8*i+5] * (v2f){xc.y, xc.y} + accH1;
      accH0 = w1f[8*i+6] * (v2f){xc.z, xc.z} + accH0;
      accH1 = w1f[8*i+7] * (v2f){xc.w, xc.w} + accH1;
    }
    v2f accH = accH0 + accH1;
    v2f accR0 = {0.f, 0.f}, accR1 = {0.f, 0.f};
    float accC0 = 0.f, accC1 = 0.f;
#pragma unroll
    for (int i = 0; i < 16; ++i) {
      float s0 = bcast(yseg, 2 * i);
      float s1 = bcast(yseg, 2 * i + 1);
      accR0 = w2f[2*i+0] * (v2f){s0, s0} + accR0;
      accR1 = w2f[2*i+1] * (v2f){s1, s1} + accR1;
      accC0 = fmaf(s0, wcf[2*i+0], accC0);
      accC1 = fmaf(s1, wcf[2*i+1], accC1);
    }
    v2f accR = accR0 + accR1;
    float accC = accC0 + accC1;

    pH[pb][kg][lane]      = accH.x;
    pH[pb][kg][lane + 64] = accH.y;
    pR[pb][kg][lane]      = accR.x;
    pR[pb][kg][lane + 64] = accR.y;
    pC[pb][kg][lane]      = accC;

    if (kg == (t & 3)) {
      if (lane < 32) {
        ((float4*)xring[(t + 8) & 15])[lane] = stg;
        int r = t + 12; r = (r < NT) ? r : (NT - 1);
        stg = xr4[r * 32 + lane];
      }
    }
    wg_barrier();
    if (lane < 32) {
      const int j = kg * 32 + lane;
      float hs = bias1, rs = bias2;
#pragma unroll
      for (int g = 0; g < 4; ++g) { hs += pH[pb][g][j]; rs += pR[pb][g][j]; }
      yseg = fast_tanh(hs) + fast_tanh(rs);
    }
    if (kg == ((t + 2) & 3) && t >= 1) {
      float cs = biasc;
#pragma unroll
      for (int g = 0; g < 4; ++g) cs += pC[pb][g][lane];
      out[((size_t)b * NT + (t - 1)) * NC + lane] = cs;
    }
  }
  float accC0 = 0.f, accC1 = 0.f;
#pragma unroll
  for (int i = 0; i < 16; ++i) {
    float s0 = bcast(yseg, 2 * i);
    float s1 = bcast(yseg, 2 * i + 1);
    accC0 = fmaf(s0, wcf[2*i+0], accC0);
    accC1 = fmaf(s1, wcf[2*i+1], accC1);
  }
  pC[0][kg][lane] = accC0 + accC1;
  wg_barrier();
  if (kg == 0) {
    float cs = biasc;
#pragma unroll
    for (int g = 0; g < 4; ++g) cs += pC[0][g][lane];
    out[((size_t)b * NT + (NT - 1)) * NC + lane] = cs;
  }
}

extern "C" void kernel_launch(void* const* d_in, const int* in_sizes, int n_in,
                              void* d_out, int out_size, void* d_ws, size_t ws_size,
                              hipStream_t stream) {
  (void)in_sizes; (void)n_in; (void)out_size;
  const float* x   = (const float*)d_in[0];
  const float* W1  = (const float*)d_in[1];
  const float* b1v = (const float*)d_in[2];
  const float* W2  = (const float*)d_in[3];
  const float* b2v = (const float*)d_in[4];
  const float* Wc  = (const float*)d_in[5];
  const float* bcv = (const float*)d_in[6];
  float* out = (float*)d_out;

  const size_t need = (size_t)NM * NU * 2;  // TH f16 = 32 MiB (no Y workspace)
  if (ws_size >= need) {
    _Float16* TH = (_Float16*)d_ws;
    hipLaunchKernelGGL(k1_inproj, dim3(NM / 64), dim3(256), 0, stream, x, W1, b1v, TH);
    hipLaunchKernelGGL(k2_recur, dim3(NB / 16), dim3(640), 0, stream,
                       TH, W2, b2v, Wc, bcv, out);
  } else {
    hipLaunchKernelGGL(rnn_fallback, dim3(NB), dim3(256), 0, stream,
                       x, W1, b1v, W2, b2v, Wc, bcv, out);
  }
}

// Round 5
// 302.313 us; speedup vs baseline: 1.3773x; 1.0039x over previous
//
#include <hip/hip_runtime.h>

#define NB 256   // batch
#define NT 512   // time steps
#define ND 128   // input dim
#define NU 128   // hidden dim
#define NC 64    // classes
#define NM (NB * NT)   // 131072 flat rows
#define YP 136         // LDS row pitch in halfs for k1 weight tile
#define SCL 2.8853900817779268f  // 2*log2(e): folds tanh 2x arg-scale + e^x -> 2^x

typedef _Float16 half2v __attribute__((ext_vector_type(2)));
typedef _Float16 half4v __attribute__((ext_vector_type(4)));
typedef _Float16 half8v __attribute__((ext_vector_type(8)));
typedef float f32x4 __attribute__((ext_vector_type(4)));
typedef float v2f __attribute__((ext_vector_type(2)));

#define MFMA(a, b, c) __builtin_amdgcn_mfma_f32_16x16x32_f16((a), (b), (c), 0, 0, 0)

// packed f32x2 -> f16x2
__device__ __forceinline__ half2v pk2(float a, float b) {
  return __builtin_bit_cast(half2v, __builtin_amdgcn_cvt_pkrtz(a, b));
}

// tanh from pre-scaled s = 2x*log2e: tanh(x) = 1 - 2/(2^s + 1); exact limits.
__device__ __forceinline__ float tanh_s(float s) {
  float e = __builtin_amdgcn_exp2f(s);
  return fmaf(-2.0f, __builtin_amdgcn_rcpf(e + 1.0f), 1.0f);
}
// y' = th + tanh(s) - 1 = th - 2/(2^s+1): the "-1" shift lets the constant
// 1-vector be folded into the next GEMM's bias via column sums of W2/Wc.
__device__ __forceinline__ float ym1(float s, float th) {
  float e = __builtin_amdgcn_exp2f(s);
  return fmaf(-2.0f, __builtin_amdgcn_rcpf(e + 1.0f), th);
}

// LDS-only barrier (no vmem drain -> prefetches/stores stay in flight).
__device__ __forceinline__ void wg_barrier() {
  asm volatile("s_waitcnt lgkmcnt(0)\n\ts_barrier" ::: "memory");
}

// ===================== K1: TH = tanh(x @ W1 + b1) -> f16 =====================
__global__ __launch_bounds__(256, 1) void k1_inproj(
    const float* __restrict__ x, const float* __restrict__ W1,
    const float* __restrict__ b1v, _Float16* __restrict__ TH)
{
  __shared__ _Float16 W1T[ND * YP];  // W1^T[n][k], pre-scaled by SCL
  const int tid = (int)threadIdx.x;
  for (int i = tid; i < ND * NU / 2; i += 256) {
    int n = i & 127, kh = i >> 7;
    half2v p = {(_Float16)(SCL * W1[(size_t)(2 * kh) * NU + n]),
                (_Float16)(SCL * W1[(size_t)(2 * kh + 1) * NU + n])};
    *(half2v*)&W1T[n * YP + 2 * kh] = p;
  }
  __syncthreads();

  const int L = tid & 63, wv = tid >> 6;
  const int v = L & 15, q = L >> 4;
  const int m0 = (int)blockIdx.x * 64 + wv * 16;

  const float* xr = x + (size_t)(m0 + v) * ND + 8 * q;
  half8v xf[4];
#pragma unroll
  for (int kk = 0; kk < 4; ++kk) {
    float4 a = *(const float4*)(xr + 32 * kk);
    float4 b = *(const float4*)(xr + 32 * kk + 4);
    half2v p0 = pk2(a.x, a.y), p1 = pk2(a.z, a.w);
    half2v p2 = pk2(b.x, b.y), p3 = pk2(b.z, b.w);
    xf[kk] = (half8v){p0[0], p0[1], p1[0], p1[1], p2[0], p2[1], p3[0], p3[1]};
  }

#pragma unroll
  for (int ht = 0; ht < 8; ++ht) {
    f32x4 acc;
    {
      float4 bb = *(const float4*)&b1v[16 * ht + 4 * q];
      acc = (f32x4){SCL * bb.x, SCL * bb.y, SCL * bb.z, SCL * bb.w};
    }
#pragma unroll
    for (int kk = 0; kk < 4; ++kk) {
      half8v wa = *(const half8v*)&W1T[(16 * ht + v) * YP + 32 * kk + 8 * q];
      acc = MFMA(wa, xf[kk], acc);
    }
    half2v zlo = pk2(tanh_s(acc[0]), tanh_s(acc[1]));
    half2v zhi = pk2(tanh_s(acc[2]), tanh_s(acc[3]));
    half4v z = {zlo[0], zlo[1], zhi[0], zhi[1]};
    *(half4v*)&TH[(size_t)(m0 + v) * NU + 16 * ht + 4 * q] = z;
  }
}

// ===================== K2: recurrence (8 waves) + head (2 waves) =====================
// 16 blocks x 640 thr. y'-image stored in B-FRAGMENT ORDER: YF[kk][lane][j]
// (frag kk at halfs kk*512, lane chunk = 16B). Read: lane L -> b128 at
// kk*1024B + L*16B -- consecutive lanes, consecutive banks, ZERO read
// conflicts (old [v][h] pitch-136 layout was an 8-way conflict, 192 cyc/step).
// Write: lane (v,q) of wave w -> one b64 at frag w>>1, lane' v+16*(2(w&1)+(q>>1)),
// half-offset 4*(q&1) (4-way conflict, 1 instr, negligible).
// Head waves read frags for y_t AFTER issuing MFMAs for y_{t-1} (off the
// post-barrier burst); rec waves run at s_setprio(1) to win LDS arbitration.
__global__ __launch_bounds__(640, 1) void k2_recur(
    const _Float16* __restrict__ TH, const float* __restrict__ W2,
    const float* __restrict__ b2v, const float* __restrict__ Wc,
    const float* __restrict__ bcv, float* __restrict__ out)
{
  __shared__ _Float16 Ybuf[2][2048];  // y' image in frag order, double-buffered

  const int tid = (int)threadIdx.x;
  const int w = tid >> 6;  // 0..7 recurrence, 8..9 head
  const int L = tid & 63;
  const int v = L & 15, q = L >> 4;
  const int b0 = (int)blockIdx.x * 16;
  const _Float16* rd = &Ybuf[0][0] + L * 8;  // lane chunk; frag kk at +kk*512
  const f32x4 zero4 = (f32x4){0.f, 0.f, 0.f, 0.f};

  if (w < 8) {
    // ---------------- recurrence wave: hidden tile [16w,16w+16) ----------------
    half8v w2f[4];  // A-frags of W2^T, scaled SCL
#pragma unroll
    for (int kk = 0; kk < 4; ++kk) {
      half8v h;
#pragma unroll
      for (int j = 0; j < 8; ++j)
        h[j] = (_Float16)(SCL * W2[(size_t)(32 * kk + 8 * q + j) * NU + 16 * w + v]);
      w2f[kk] = h;
    }
    f32x4 racc, b2f;
    {
      const int h0 = 16 * w + 4 * q;
      float4 bb = *(const float4*)&b2v[h0];
      racc = (f32x4){SCL * bb.x, SCL * bb.y, SCL * bb.z, SCL * bb.w};
      // b2' = SCL*(b2 + sum_k W2[k,:])  (y-1 shift fold); racc stays SCL*b2.
      f32x4 cs = zero4;
#pragma unroll 4
      for (int k = 0; k < NU; ++k) {
        float4 ww = *(const float4*)&W2[(size_t)k * NU + h0];
        cs += (f32x4){ww.x, ww.y, ww.z, ww.w};
      }
      b2f = racc + (f32x4){SCL * cs[0], SCL * cs[1], SCL * cs[2], SCL * cs[3]};
    }

    const _Float16* thp = TH + ((size_t)(b0 + v) * NT) * NU + 16 * w + 4 * q;
    // write slot in frag order: frag w>>1, lane' = v + 16*(2*(w&1)+(q>>1)),
    // half offset 4*(q&1)
    _Float16* wr = &Ybuf[0][0] + (w >> 1) * 512 +
                   (v + 16 * (2 * (w & 1) + (q >> 1))) * 8 + 4 * (q & 1);

    // th prefetch ring (4 deep), one 8B load per step
    half4v thr0 = *(const half4v*)(thp + 0 * NU);
    half4v thr1 = *(const half4v*)(thp + 1 * NU);
    half4v thr2 = *(const half4v*)(thp + 2 * NU);
    half4v thr3 = *(const half4v*)(thp + 3 * NU);

    __builtin_amdgcn_s_setprio(1);  // critical-chain waves win LDS arbitration

#define RSTEP(T_, THR_, BUF_)                                                 \
  {                                                                           \
    half2v ylo = pk2(ym1(racc[0], (float)THR_[0]),                            \
                     ym1(racc[1], (float)THR_[1]));                           \
    half2v yhi = pk2(ym1(racc[2], (float)THR_[2]),                            \
                     ym1(racc[3], (float)THR_[3]));                           \
    half4v y4 = {ylo[0], ylo[1], yhi[0], yhi[1]};                             \
    *(half4v*)(wr + (BUF_) * 2048) = y4;                                      \
    {                                                                         \
      int tn = (T_) + 4; tn = tn < NT ? tn : NT - 1;                          \
      THR_ = *(const half4v*)(thp + (size_t)tn * NU);                         \
    }                                                                         \
    wg_barrier();                                                             \
    {                                                                         \
      half8v yf0 = *(const half8v*)(rd + (BUF_) * 2048 + 0);                  \
      half8v yf1 = *(const half8v*)(rd + (BUF_) * 2048 + 512);                \
      half8v yf2 = *(const half8v*)(rd + (BUF_) * 2048 + 1024);               \
      half8v yf3 = *(const half8v*)(rd + (BUF_) * 2048 + 1536);               \
      f32x4 ra = MFMA(w2f[0], yf0, b2f);  /* two independent 2-chains */      \
      f32x4 rb = MFMA(w2f[1], yf1, zero4);                                    \
      ra = MFMA(w2f[2], yf2, ra);                                             \
      rb = MFMA(w2f[3], yf3, rb);                                             \
      racc = ra + rb;                                                         \
    }                                                                         \
  }

#pragma unroll 1
    for (int t = 0; t < NT; t += 4) {
      RSTEP(t + 0, thr0, 0)
      RSTEP(t + 1, thr1, 1)
      RSTEP(t + 2, thr2, 0)
      RSTEP(t + 3, thr3, 1)
    }
#undef RSTEP
  } else {
    // ---------------- head wave hw = w-8: class tiles {2hw, 2hw+1} ----------------
    const int hw = w - 8;
    half8v wcf[2][4];
    f32x4 bcf[2];
#pragma unroll
    for (int c2 = 0; c2 < 2; ++c2) {
      const int ct = 2 * hw + c2;
#pragma unroll
      for (int kk = 0; kk < 4; ++kk) {
        half8v h;
#pragma unroll
        for (int j = 0; j < 8; ++j)
          h[j] = (_Float16)Wc[(size_t)(32 * kk + 8 * q + j) * NC + 16 * ct + v];
        wcf[c2][kk] = h;
      }
      const int c0 = 16 * ct + 4 * q;
      float4 bb = *(const float4*)&bcv[c0];
      f32x4 cs = zero4;  // bc' = bc + sum_k Wc[k,:] (y-1 shift fold)
#pragma unroll 4
      for (int k = 0; k < NU; ++k) {
        float4 ww = *(const float4*)&Wc[(size_t)k * NC + c0];
        cs += (f32x4){ww.x, ww.y, ww.z, ww.w};
      }
      bcf[c2] = cs + (f32x4){bb.x, bb.y, bb.z, bb.w};
    }
    float* op = out + ((size_t)(b0 + v) * NT) * NC + 4 * q + 32 * hw;

    // Pipelined: reads for y_t issue after the MFMAs for y_{t-1}, landing in
    // the LDS-quiet window (rec waves are in MFMA/tanh). Frags carried in regs
    // across the barrier. Double-buffer-safe: reads drain at our lgkmcnt(0)
    // before barrier t+1; buf[t&1] is only rewritten (y_{t+2}) after that.
    half8v pf0, pf1, pf2, pf3;
#pragma unroll 1
    for (int t = 0; t < NT; ++t) {
      wg_barrier();  // barrier #t: y_t now visible in buf[t&1]
      if (t > 0) {
#pragma unroll
        for (int c2 = 0; c2 < 2; ++c2) {
          f32x4 oa = MFMA(wcf[c2][0], pf0, bcf[c2]);
          f32x4 ob = MFMA(wcf[c2][1], pf1, zero4);
          oa = MFMA(wcf[c2][2], pf2, oa);
          ob = MFMA(wcf[c2][3], pf3, ob);
          f32x4 oo = oa + ob;
          *(float4*)(op + (size_t)(t - 1) * NC + 16 * c2) =
              (float4){oo[0], oo[1], oo[2], oo[3]};
        }
      }
      const _Float16* rb = rd + (t & 1) * 2048;
      pf0 = *(const half8v*)(rb + 0);
      pf1 = *(const half8v*)(rb + 512);
      pf2 = *(const half8v*)(rb + 1024);
      pf3 = *(const half8v*)(rb + 1536);
    }
    asm volatile("s_waitcnt lgkmcnt(0)" ::: "memory");
#pragma unroll
    for (int c2 = 0; c2 < 2; ++c2) {
      f32x4 oa = MFMA(wcf[c2][0], pf0, bcf[c2]);
      f32x4 ob = MFMA(wcf[c2][1], pf1, zero4);
      oa = MFMA(wcf[c2][2], pf2, oa);
      ob = MFMA(wcf[c2][3], pf3, ob);
      f32x4 oo = oa + ob;
      *(float4*)(op + (size_t)(NT - 1) * NC + 16 * c2) =
          (float4){oo[0], oo[1], oo[2], oo[3]};
    }
  }
}

// ===================== fallback (round-2 kernel, no workspace) =====================
__device__ __forceinline__ float fast_tanh(float x) {
  float e = __expf(2.0f * x);
  return 1.0f - 2.0f / (e + 1.0f);
}
__device__ __forceinline__ float bcast(float val, int i) {
  return __builtin_bit_cast(float, __builtin_amdgcn_readlane(__builtin_bit_cast(int, val), i));
}

__global__ __launch_bounds__(256, 1) void rnn_fallback(
    const float* __restrict__ x, const float* __restrict__ W1,
    const float* __restrict__ b1v, const float* __restrict__ W2,
    const float* __restrict__ b2v, const float* __restrict__ Wc,
    const float* __restrict__ bcv, float* __restrict__ out)
{
  __shared__ float xring[16][ND];
  __shared__ float pH[2][4][NU];
  __shared__ float pR[2][4][NU];
  __shared__ float pC[2][4][NC];

  const int tid  = (int)threadIdx.x;
  const int lane = tid & 63;
  const int kg   = tid >> 6;
  const int b    = (int)blockIdx.x;
  const float4* xr4 = (const float4*)(x + (size_t)b * NT * ND);

  v2f w1f[32], w2f[32];
  float wcf[32];
#pragma unroll
  for (int i = 0; i < 32; ++i) {
    int k = kg * 32 + i;
    w1f[i] = (v2f){W1[k * NU + lane], W1[k * NU + lane + 64]};
    w2f[i] = (v2f){W2[k * NU + lane], W2[k * NU + lane + 64]};
    wcf[i] = Wc[k * NC + lane];
  }
  const float biasc = bcv[lane];
  float bias1 = 0.f, bias2 = 0.f;
  if (lane < 32) { bias1 = b1v[kg * 32 + lane]; bias2 = b2v[kg * 32 + lane]; }

  float4 stg = make_float4(0.f, 0.f, 0.f, 0.f);
  if (lane < 32) {
    float4 a0 = xr4[(kg + 0) * 32 + lane];
    float4 a1 = xr4[(kg + 4) * 32 + lane];
    ((float4*)xring[kg + 0])[lane] = a0;
    ((float4*)xring[kg + 4])[lane] = a1;
    stg = xr4[(kg + 8) * 32 + lane];
  }
  float yseg = 0.f;
  wg_barrier();

  for (int t = 0; t < NT; ++t) {
    const int pb = t & 1;
    v2f accH0 = {0.f, 0.f}, accH1 = {0.f, 0.f};
    const float4* xb = (const float4*)&xring[t & 15][kg * 32];
#pragma unroll
    for (int i = 0; i < 4; ++i) {
      float4 xa = xb[2 * i];
      float4 xc = xb[2 * i + 1];
      accH0 = w1f[8*i+0] * (v2f){xa.x, xa.x} + accH0;
      accH1 = w1f[8*i+1] * (v2f){xa.y, xa.y} + accH1;
      accH0 = w1f[8*i+2] * (v2f){xa.z, xa.z} + accH0;
      accH1 = w1f[8*i+3] * (v2f){xa.w, xa.w} + accH1;
      accH0 = w1f[8*i+4] * (v2f){xc.x, xc.x} + accH0;
      accH1 = w1f[8*i+5] * (v2f){xc.y, xc.y} + accH1;
      accH0 = w1f[8*i+6] * (v2f){xc.z, xc.z} + accH0;
      accH1 = w1f[8*i+7] * (v2f){xc.w, xc.w} + accH1;
    }
    v2f accH = accH0 + accH1;
    v2f accR0 = {0.f, 0.f}, accR1 = {0.f, 0.f};
    float accC0 = 0.f, accC1 = 0.f;
#pragma unroll
    for (int i = 0; i < 16; ++i) {
      float s0 = bcast(yseg, 2 * i);
      float s1 = bcast(yseg, 2 * i + 1);
      accR0 = w2f[2*i+0] * (v2f){s0, s0} + accR0;
      accR1 = w2f[2*i+1] * (v2f){s1, s1} + accR1;
      accC0 = fmaf(s0, wcf[2*i+0], accC0);
      accC1 = fmaf(s1, wcf[2*i+1], accC1);
    }
    v2f accR = accR0 + accR1;
    float accC = accC0 + accC1;

    pH[pb][kg][lane]      = accH.x;
    pH[pb][kg][lane + 64] = accH.y;
    pR[pb][kg][lane]      = accR.x;
    pR[pb][kg][lane + 64] = accR.y;
    pC[pb][kg][lane]      = accC;

    if (kg == (t & 3)) {
      if (lane < 32) {
        ((float4*)xring[(t + 8) & 15])[lane] = stg;
        int r = t + 12; r = (r < NT) ? r : (NT - 1);
        stg = xr4[r * 32 + lane];
      }
    }
    wg_barrier();
    if (lane < 32) {
      const int j = kg * 32 + lane;
      float hs = bias1, rs = bias2;
#pragma unroll
      for (int g = 0; g < 4; ++g) { hs += pH[pb][g][j]; rs += pR[pb][g][j]; }
      yseg = fast_tanh(hs) + fast_tanh(rs);
    }
    if (kg == ((t + 2) & 3) && t >= 1) {
      float cs = biasc;
#pragma unroll
      for (int g = 0; g < 4; ++g) cs += pC[pb][g][lane];
      out[((size_t)b * NT + (t - 1)) * NC + lane] = cs;
    }
  }
  float accC0 = 0.f, accC1 = 0.f;
#pragma unroll
  for (int i = 0; i < 16; ++i) {
    float s0 = bcast(yseg, 2 * i);
    float s1 = bcast(yseg, 2 * i + 1);
    accC0 = fmaf(s0, wcf[2*i+0], accC0);
    accC1 = fmaf(s1, wcf[2*i+1], accC1);
  }
  pC[0][kg][lane] = accC0 + accC1;
  wg_barrier();
  if (kg == 0) {
    float cs = biasc;
#pragma unroll
    for (int g = 0; g < 4; ++g) cs += pC[0][g][lane];
    out[((size_t)b * NT + (NT - 1)) * NC + lane] = cs;
  }
}

extern "C" void kernel_launch(void* const* d_in, const int* in_sizes, int n_in,
                              void* d_out, int out_size, void* d_ws, size_t ws_size,
                              hipStream_t stream) {
  (void)in_sizes; (void)n_in; (void)out_size;
  const float* x   = (const float*)d_in[0];
  const float* W1  = (const float*)d_in[1];
  const float* b1v = (const float*)d_in[2];
  const float* W2  = (const float*)d_in[3];
  const float* b2v = (const float*)d_in[4];
  const float* Wc  = (const float*)d_in[5];
  const float* bcv = (const float*)d_in[6];
  float* out = (float*)d_out;

  const size_t need = (size_t)NM * NU * 2;  // TH f16 = 32 MiB (no Y workspace)
  if (ws_size >= need) {
    _Float16* TH = (_Float16*)d_ws;
    hipLaunchKernelGGL(k1_inproj, dim3(NM / 64), dim3(256), 0, stream, x, W1, b1v, TH);
    hipLaunchKernelGGL(k2_recur, dim3(NB / 16), dim3(640), 0, stream,
                       TH, W2, b2v, Wc, bcv, out);
  } else {
    hipLaunchKernelGGL(rnn_fallback, dim3(NB), dim3(256), 0, stream,
                       x, W1, b1v, W2, b2v, Wc, bcv, out);
  }
}